// Round 2
// baseline (444.116 us; speedup 1.0000x reference)
//
#include <hip/hip_runtime.h>
#include <math.h>
#include <float.h>

#define MAX_DET 25
#define IOU_THRES 0.7f
#define MAX_WH 7680.0f
#define NBIN 2048
#define TOPK 256
#define MCAP 512
#define N_TOTAL 403200

__device__ __forceinline__ float sigm(float v) {
#pragma clang fp contract(off)
    return 1.0f / (1.0f + expf(-v));
}

// ---------------- Decode: 16 lanes per candidate ----------------
template<int NY, int NX>
__global__ __launch_bounds__(256) void decode_kernel(
    const float* __restrict__ x, const float* __restrict__ anch,
    float* __restrict__ confW, float* __restrict__ boxW,
    unsigned* __restrict__ hist, int grpBase)
{
#pragma clang fp contract(off)
    constexpr int HW = NY * NX;
    constexpr int NPC = 3 * HW;
    constexpr int N = 16 * NPC;
    int t = blockIdx.x * 256 + threadIdx.x;
    int g = t >> 4;
    if (g >= N) return;
    int l16 = t & 15;
    const float* row = x + (long)g * 85;

    // max over 80 class logits, tie -> lowest class index
    float bv = -FLT_MAX; int bc = 0;
#pragma unroll
    for (int j = 0; j < 5; ++j) {
        float v = row[5 + l16 + 16 * j];
        if (v > bv) { bv = v; bc = l16 + 16 * j; }
    }
#pragma unroll
    for (int off = 8; off; off >>= 1) {
        float ov = __shfl_xor(bv, off);
        int   oc = __shfl_xor(bc, off);
        if (ov > bv || (ov == bv && oc < bc)) { bv = ov; bc = oc; }
    }
    if (l16 != 0) return;

    float v0 = row[0], v1 = row[1], v2 = row[2], v3 = row[3], v4 = row[4];
    int i   = g % NPC;
    int a   = i / HW;
    int rem = i - a * HW;
    int gy  = rem / NX;
    int gx  = rem - gy * NX;

    float conf = sigm(bv) * sigm(v4);
    float cx = sigm(v0) * 2.0f + ((float)gx - 0.5f);
    float cy = sigm(v1) * 2.0f + ((float)gy - 0.5f);
    float tw = sigm(v2) * 2.0f, th = sigm(v3) * 2.0f;
    float w = (tw * tw) * anch[a * 2 + 0];
    float h = (th * th) * anch[a * 2 + 1];
    float x1 = cx - w / 2.0f, y1 = cy - h / 2.0f;
    float x2 = cx + w / 2.0f, y2 = cy + h / 2.0f;
    float offc = (float)bc * MAX_WH;

    confW[g] = conf;
    float4 bb = make_float4(x1 + offc, y1 + offc, x2 + offc, y2 + offc);
    *reinterpret_cast<float4*>(boxW + (long)g * 4) = bb;

    // histogram of conf bits (conf in (0,1) -> bits monotone, bin < 2048)
    int b = g / NPC;
    unsigned bin = __float_as_uint(conf) >> 19;
    atomicAdd(&hist[(grpBase + b) * NBIN + bin], 1u);
}

// ---------------- Per-group threshold: K-th largest conf bin ----------------
__global__ __launch_bounds__(256) void thresh_kernel(
    const unsigned* __restrict__ hist, unsigned* __restrict__ thrBits)
{
    __shared__ unsigned csum[256];
    int grp = blockIdx.x;
    const unsigned* h = hist + grp * NBIN;
    int tid = threadIdx.x;
    unsigned s = 0;
#pragma unroll
    for (int j = 0; j < 8; ++j) s += h[NBIN - 1 - (tid * 8 + j)];
    csum[tid] = s;
    __syncthreads();
    if (tid == 0) {
        unsigned acc = 0; int thrBin = 0;
        for (int c = 0; c < 256; ++c) {
            if (acc + csum[c] >= TOPK) {
                for (int j = 0; j < 8; ++j) {
                    int bin = NBIN - 1 - (c * 8 + j);
                    acc += h[bin];
                    if (acc >= TOPK) { thrBin = bin; break; }
                }
                break;
            }
            acc += csum[c];
        }
        thrBits[grp] = (unsigned)thrBin << 19;
    }
}

// ---------------- Collect candidates above threshold ----------------
__global__ __launch_bounds__(256) void collect_kernel(
    const float* __restrict__ confW, const unsigned* __restrict__ thrBits,
    unsigned* __restrict__ cnt, unsigned long long* __restrict__ keys)
{
    int g = blockIdx.x * 256 + threadIdx.x;
    if (g >= N_TOTAL) return;
    int grp, li;
    if (g < 307200)      { int b = g / 19200;               grp = b;      li = g - b * 19200; }
    else if (g < 384000) { int gg = g - 307200; int b = gg / 4800; grp = 16 + b; li = gg - b * 4800; }
    else                 { int gg = g - 384000; int b = gg / 1200; grp = 32 + b; li = gg - b * 1200; }
    unsigned bits = __float_as_uint(confW[g]);
    if (bits >= thrBits[grp]) {
        unsigned pos = atomicAdd(&cnt[grp], 1u);
        if (pos < MCAP)
            keys[grp * MCAP + pos] = ((unsigned long long)bits << 32) | (unsigned)(~li);
    }
}

// ---------------- NMS (sorted top-K) + feature gather ----------------
struct LvlParams {
    const float* feat;
    long candOff;
    long outOff;
    int npc, ny, nx, C;
};

__global__ __launch_bounds__(256) void nms_gather_kernel(
    const float* __restrict__ boxW, const unsigned* __restrict__ cnt,
    const unsigned long long* __restrict__ keys, float* __restrict__ out,
    LvlParams p0, LvlParams p1, LvlParams p2)
{
#pragma clang fp contract(off)
    __shared__ unsigned long long sk[MCAP];
    __shared__ float sbox[128][4];
    __shared__ float selBox[MAX_DET][4];
    __shared__ int   selIdx[MAX_DET];
    __shared__ int   selValid[MAX_DET];

    int grp = blockIdx.x;
    int lvl = grp >> 4, b = grp & 15;
    LvlParams p = (lvl == 0) ? p0 : ((lvl == 1) ? p1 : p2);
    int tid = threadIdx.x;
    unsigned cn = cnt[grp];
    int n = (cn < (unsigned)MCAP) ? (int)cn : MCAP;
    const unsigned long long* gk = keys + grp * MCAP;
    for (int i = tid; i < MCAP; i += 256) sk[i] = (i < n) ? gk[i] : 0ULL;
    if (tid < MAX_DET) selValid[tid] = 0;
    __syncthreads();

    // bitonic sort descending (unique keys -> deterministic total order)
    for (int ksz = 2; ksz <= MCAP; ksz <<= 1) {
        for (int j = ksz >> 1; j > 0; j >>= 1) {
            for (int i = tid; i < MCAP; i += 256) {
                int ixj = i ^ j;
                if (ixj > i) {
                    unsigned long long a = sk[i], bb = sk[ixj];
                    bool desc = ((i & ksz) == 0);
                    if (desc ? (a < bb) : (a > bb)) { sk[i] = bb; sk[ixj] = a; }
                }
            }
            __syncthreads();
        }
    }

    // prefetch top-128 boxes
    const long base4 = (p.candOff + (long)b * p.npc) * 4;
    if (tid < 128 && tid < n) {
        int idx = (int)(~(unsigned)sk[tid]);
        const float4 bb4 = *reinterpret_cast<const float4*>(boxW + base4 + (long)idx * 4);
        sbox[tid][0] = bb4.x; sbox[tid][1] = bb4.y; sbox[tid][2] = bb4.z; sbox[tid][3] = bb4.w;
    }
    __syncthreads();

    // serial greedy NMS on wave 0 (examines ~25+rejections candidates)
    if (tid < 64) {
        int k = 0;
        for (int t = 0; t < n && k < MAX_DET; ++t) {
            float cx1, cy1, cx2, cy2;
            if (t < 128) {
                cx1 = sbox[t][0]; cy1 = sbox[t][1]; cx2 = sbox[t][2]; cy2 = sbox[t][3];
            } else {
                int idx = (int)(~(unsigned)sk[t]);
                const float* bp = boxW + base4 + (long)idx * 4;
                cx1 = bp[0]; cy1 = bp[1]; cx2 = bp[2]; cy2 = bp[3];
            }
            bool rej = false;
            if (tid < k) {
                float sx1 = selBox[tid][0], sy1 = selBox[tid][1];
                float sx2 = selBox[tid][2], sy2 = selBox[tid][3];
                float ltx = fmaxf(sx1, cx1), lty = fmaxf(sy1, cy1);
                float rbx = fminf(sx2, cx2), rby = fminf(sy2, cy2);
                float ww = fmaxf(rbx - ltx, 0.0f), hh = fmaxf(rby - lty, 0.0f);
                float inter = ww * hh;
                float area1 = (sx2 - sx1) * (sy2 - sy1);
                float area2 = (cx2 - cx1) * (cy2 - cy1);
                float iou = inter / (area1 + area2 - inter);
                rej = iou > IOU_THRES;
            }
            rej = __any(rej);
            if (!rej) {
                if (tid == 0) {
                    selIdx[k] = (int)(~(unsigned)sk[t]);
                    selValid[k] = 1;
                    selBox[k][0] = cx1; selBox[k][1] = cy1;
                    selBox[k][2] = cx2; selBox[k][3] = cy2;
                }
                k++;
            }
        }
    }
    __syncthreads();

    // gather features
    const int hw = p.ny * p.nx;
    for (int k2 = 0; k2 < MAX_DET; ++k2) {
        long obase = p.outOff + ((long)b * MAX_DET + k2) * p.C;
        if (selValid[k2]) {
            int idx = selIdx[k2];
            int rem = idx % hw;
            int gy = rem / p.nx, gx = rem - gy * p.nx;
            const float* f = p.feat + (long)b * p.C * hw + (long)gy * p.nx + gx;
            for (int c = tid; c < p.C; c += 256)
                out[obase + c] = f[(long)c * hw];
        } else {
            for (int c = tid; c < p.C; c += 256)
                out[obase + c] = 0.0f;
        }
    }
}

extern "C" void kernel_launch(void* const* d_in, const int* in_sizes, int n_in,
                              void* d_out, int out_size, void* d_ws, size_t ws_size,
                              hipStream_t stream)
{
    const float* xs[3] = {nullptr, nullptr, nullptr};
    const float* fs[3] = {nullptr, nullptr, nullptr};
    const float* anch  = nullptr;
    for (int i = 0; i < n_in; ++i) {
        const float* p = (const float*)d_in[i];
        switch (in_sizes[i]) {
            case 26112000: xs[0] = p; break;
            case 6528000:  xs[1] = p; break;
            case 1632000:  xs[2] = p; break;
            case 13107200: fs[0] = p; break;
            case 6553600:  fs[1] = p; break;
            case 3276800:  fs[2] = p; break;
            case 18:       anch  = p; break;
        }
    }

    char* wsb = (char*)d_ws;
    float*              confW = (float*)wsb;                                   // 403200 f32
    float*              boxW  = (float*)(wsb + 1612800L);                      // 403200 f32x4
    unsigned*           hist  = (unsigned*)(wsb + 8064000L);                   // 48*2048 u32
    unsigned*           cntW  = (unsigned*)(wsb + 8064000L + 48L * NBIN * 4);  // 48 u32
    unsigned*           thrW  = (unsigned*)(wsb + 8064000L + 48L * NBIN * 4 + 192L);
    unsigned long long* keys  = (unsigned long long*)(wsb + 8457600L);         // 48*512 u64

    // zero hist + cnt (d_ws is NOT re-poisoned between replays)
    hipMemsetAsync(hist, 0, 48L * NBIN * 4 + 192L, stream);

    decode_kernel<80, 80><<<19200, 256, 0, stream>>>(xs[0], anch + 0,  confW + 0,      boxW + 0L,            hist, 0);
    decode_kernel<40, 40><<<4800,  256, 0, stream>>>(xs[1], anch + 6,  confW + 307200, boxW + 307200L * 4,   hist, 16);
    decode_kernel<20, 20><<<1200,  256, 0, stream>>>(xs[2], anch + 12, confW + 384000, boxW + 384000L * 4,   hist, 32);

    thresh_kernel<<<48, 256, 0, stream>>>(hist, thrW);
    collect_kernel<<<(N_TOTAL + 255) / 256, 256, 0, stream>>>(confW, thrW, cntW, keys);

    LvlParams P0{fs[0], 0L,      0L,      19200, 80, 80, 128};
    LvlParams P1{fs[1], 307200L, 51200L,  4800,  40, 40, 256};
    LvlParams P2{fs[2], 384000L, 153600L, 1200,  20, 20, 512};

    nms_gather_kernel<<<48, 256, 0, stream>>>(boxW, cntW, keys, (float*)d_out, P0, P1, P2);
}

// Round 3
// 115.116 us; speedup vs baseline: 3.8580x; 3.8580x over previous
//
#include <hip/hip_runtime.h>
#include <math.h>
#include <float.h>

#define MAX_DET 25
#define IOU_THRES 0.7f
#define MAX_WH 7680.0f
#define TOPK 256
#define MCAP 512

__device__ __forceinline__ float sigm(float v) {
#pragma clang fp contract(off)
    return 1.0f / (1.0f + expf(-v));
}

// ---------------- Decode: 16 lanes per candidate (round-1 form, no atomics) ----------------
template<int NY, int NX>
__global__ __launch_bounds__(256) void decode_kernel(
    const float* __restrict__ x, const float* __restrict__ anch,
    float* __restrict__ confW, float* __restrict__ boxW)
{
#pragma clang fp contract(off)
    constexpr int HW = NY * NX;
    constexpr int NPC = 3 * HW;
    constexpr int N = 16 * NPC;
    int t = blockIdx.x * 256 + threadIdx.x;
    int g = t >> 4;
    if (g >= N) return;
    int l16 = t & 15;
    const float* row = x + (long)g * 85;

    // max over 80 class logits, tie -> lowest class index
    float bv = -FLT_MAX; int bc = 0;
#pragma unroll
    for (int j = 0; j < 5; ++j) {
        float v = row[5 + l16 + 16 * j];
        if (v > bv) { bv = v; bc = l16 + 16 * j; }
    }
#pragma unroll
    for (int off = 8; off; off >>= 1) {
        float ov = __shfl_xor(bv, off);
        int   oc = __shfl_xor(bc, off);
        if (ov > bv || (ov == bv && oc < bc)) { bv = ov; bc = oc; }
    }
    if (l16 != 0) return;

    float v0 = row[0], v1 = row[1], v2 = row[2], v3 = row[3], v4 = row[4];
    int i   = g % NPC;
    int a   = i / HW;
    int rem = i - a * HW;
    int gy  = rem / NX;
    int gx  = rem - gy * NX;

    float conf = sigm(bv) * sigm(v4);
    float cx = sigm(v0) * 2.0f + ((float)gx - 0.5f);
    float cy = sigm(v1) * 2.0f + ((float)gy - 0.5f);
    float tw = sigm(v2) * 2.0f, th = sigm(v3) * 2.0f;
    float w = (tw * tw) * anch[a * 2 + 0];
    float h = (th * th) * anch[a * 2 + 1];
    float x1 = cx - w / 2.0f, y1 = cy - h / 2.0f;
    float x2 = cx + w / 2.0f, y2 = cy + h / 2.0f;
    float offc = (float)bc * MAX_WH;

    confW[g] = conf;
    float4 bb = make_float4(x1 + offc, y1 + offc, x2 + offc, y2 + offc);
    *reinterpret_cast<float4*>(boxW + (long)g * 4) = bb;
}

// ---------------- Fused per-group: topK-select + sort + NMS + gather ----------------
struct LvlParams {
    const float* feat;
    long candOff;
    long outOff;
    int npc, ny, nx, C;
};

template<int NPC>
__device__ __forceinline__ void run_group(
    const float* __restrict__ gconf, const float* __restrict__ boxW, long base4,
    unsigned long long* sk, float (*sbox)[4], float (*selBox)[4],
    int* selIdx, int* selValid, unsigned* lcnt /*8*/, unsigned* misc /*2*/,
    const LvlParams& p, int b, float* __restrict__ out)
{
#pragma clang fp contract(off)
    constexpr int NR = (NPC + 255) / 256;
    const int tid = threadIdx.x;

    // load this group's conf bits into registers (coalesced stripes)
    unsigned ub[NR];
#pragma unroll
    for (int j = 0; j < NR; ++j) {
        int idx = tid + j * 256;
        ub[j] = ((NPC % 256 == 0) || idx < NPC) ? __float_as_uint(gconf[idx]) : 0u;
    }
    if (tid < MAX_DET) selValid[tid] = 0;
    if (tid == 0) misc[0] = 0;
    for (int i = tid; i < MCAP; i += 256) sk[i] = 0ULL;

    // binary search for the TOPK-th largest conf bit-pattern (conf in (0,1))
    unsigned lo = 0, hi = 0x3F800000u;
    for (int it = 0; it < 30; ++it) {
        unsigned mid = (lo + hi) >> 1;
        unsigned c = 0;
#pragma unroll
        for (int j = 0; j < NR; ++j) c += (ub[j] >= mid) ? 1u : 0u;
#pragma unroll
        for (int off = 32; off; off >>= 1) c += __shfl_down(c, off);
        int par = (it & 1) * 4;
        if ((tid & 63) == 0) lcnt[par + (tid >> 6)] = c;
        __syncthreads();
        unsigned total = lcnt[par + 0] + lcnt[par + 1] + lcnt[par + 2] + lcnt[par + 3];
        if (total >= TOPK) lo = mid; else hi = mid;
    }
    __syncthreads();

    // collect {bits >= lo} into LDS key list (set is deterministic; order fixed by sort)
#pragma unroll
    for (int j = 0; j < NR; ++j) {
        int idx = tid + j * 256;
        bool in = ((NPC % 256 == 0) || idx < NPC) && (ub[j] >= lo);
        if (in) {
            unsigned pos = atomicAdd(&misc[0], 1u);
            if (pos < MCAP)
                sk[pos] = ((unsigned long long)ub[j] << 32) | (unsigned)(~idx);
        }
    }
    __syncthreads();
    unsigned cn = misc[0];
    int n = (cn < (unsigned)MCAP) ? (int)cn : MCAP;

    // bitonic sort descending (keys unique -> deterministic; tie conf -> smaller idx first)
    for (int ksz = 2; ksz <= MCAP; ksz <<= 1) {
        for (int j = ksz >> 1; j > 0; j >>= 1) {
            for (int i = tid; i < MCAP; i += 256) {
                int ixj = i ^ j;
                if (ixj > i) {
                    unsigned long long a = sk[i], bb = sk[ixj];
                    bool desc = ((i & ksz) == 0);
                    if (desc ? (a < bb) : (a > bb)) { sk[i] = bb; sk[ixj] = a; }
                }
            }
            __syncthreads();
        }
    }

    // prefetch top-128 boxes to LDS
    if (tid < 128 && tid < n) {
        int idx = (int)(~(unsigned)sk[tid]);
        const float4 bb4 = *reinterpret_cast<const float4*>(boxW + base4 + (long)idx * 4);
        sbox[tid][0] = bb4.x; sbox[tid][1] = bb4.y; sbox[tid][2] = bb4.z; sbox[tid][3] = bb4.w;
    }
    __syncthreads();

    // serial greedy NMS on wave 0
    if (tid < 64) {
        int k = 0;
        for (int t = 0; t < n && k < MAX_DET; ++t) {
            float cx1, cy1, cx2, cy2;
            if (t < 128) {
                cx1 = sbox[t][0]; cy1 = sbox[t][1]; cx2 = sbox[t][2]; cy2 = sbox[t][3];
            } else {
                int idx = (int)(~(unsigned)sk[t]);
                const float* bp = boxW + base4 + (long)idx * 4;
                cx1 = bp[0]; cy1 = bp[1]; cx2 = bp[2]; cy2 = bp[3];
            }
            bool rej = false;
            if (tid < k) {
                float sx1 = selBox[tid][0], sy1 = selBox[tid][1];
                float sx2 = selBox[tid][2], sy2 = selBox[tid][3];
                float ltx = fmaxf(sx1, cx1), lty = fmaxf(sy1, cy1);
                float rbx = fminf(sx2, cx2), rby = fminf(sy2, cy2);
                float ww = fmaxf(rbx - ltx, 0.0f), hh = fmaxf(rby - lty, 0.0f);
                float inter = ww * hh;
                float area1 = (sx2 - sx1) * (sy2 - sy1);
                float area2 = (cx2 - cx1) * (cy2 - cy1);
                float iou = inter / (area1 + area2 - inter);
                rej = iou > IOU_THRES;
            }
            rej = __any(rej);
            if (!rej) {
                if (tid == 0) {
                    selIdx[k] = (int)(~(unsigned)sk[t]);
                    selValid[k] = 1;
                    selBox[k][0] = cx1; selBox[k][1] = cy1;
                    selBox[k][2] = cx2; selBox[k][3] = cy2;
                }
                k++;
            }
        }
    }
    __syncthreads();

    // gather features for the 25 output slots
    const int hw = p.ny * p.nx;
    for (int k2 = 0; k2 < MAX_DET; ++k2) {
        long obase = p.outOff + ((long)b * MAX_DET + k2) * p.C;
        if (selValid[k2]) {
            int idx = selIdx[k2];
            int rem = idx % hw;
            int gy = rem / p.nx, gx = rem - gy * p.nx;
            const float* f = p.feat + (long)b * p.C * hw + (long)gy * p.nx + gx;
            for (int c = tid; c < p.C; c += 256)
                out[obase + c] = f[(long)c * hw];
        } else {
            for (int c = tid; c < p.C; c += 256)
                out[obase + c] = 0.0f;
        }
    }
}

__global__ __launch_bounds__(256) void select_nms_gather_kernel(
    const float* __restrict__ confW, const float* __restrict__ boxW,
    float* __restrict__ out, LvlParams p0, LvlParams p1, LvlParams p2)
{
    __shared__ unsigned long long sk[MCAP];
    __shared__ float sbox[128][4];
    __shared__ float selBox[MAX_DET][4];
    __shared__ int   selIdx[MAX_DET];
    __shared__ int   selValid[MAX_DET];
    __shared__ unsigned lcnt[8];
    __shared__ unsigned misc[2];

    int grp = blockIdx.x;
    int lvl = grp >> 4, b = grp & 15;
    if (lvl == 0) {
        long base = p0.candOff + (long)b * p0.npc;
        run_group<19200>(confW + base, boxW, base * 4, sk, sbox, selBox, selIdx, selValid, lcnt, misc, p0, b, out);
    } else if (lvl == 1) {
        long base = p1.candOff + (long)b * p1.npc;
        run_group<4800>(confW + base, boxW, base * 4, sk, sbox, selBox, selIdx, selValid, lcnt, misc, p1, b, out);
    } else {
        long base = p2.candOff + (long)b * p2.npc;
        run_group<1200>(confW + base, boxW, base * 4, sk, sbox, selBox, selIdx, selValid, lcnt, misc, p2, b, out);
    }
}

extern "C" void kernel_launch(void* const* d_in, const int* in_sizes, int n_in,
                              void* d_out, int out_size, void* d_ws, size_t ws_size,
                              hipStream_t stream)
{
    const float* xs[3] = {nullptr, nullptr, nullptr};
    const float* fs[3] = {nullptr, nullptr, nullptr};
    const float* anch  = nullptr;
    for (int i = 0; i < n_in; ++i) {
        const float* p = (const float*)d_in[i];
        switch (in_sizes[i]) {
            case 26112000: xs[0] = p; break;
            case 6528000:  xs[1] = p; break;
            case 1632000:  xs[2] = p; break;
            case 13107200: fs[0] = p; break;
            case 6553600:  fs[1] = p; break;
            case 3276800:  fs[2] = p; break;
            case 18:       anch  = p; break;
        }
    }

    char* wsb = (char*)d_ws;
    float* confW = (float*)wsb;                  // 403200 f32
    float* boxW  = (float*)(wsb + 1612800L);     // 403200 f32x4

    decode_kernel<80, 80><<<19200, 256, 0, stream>>>(xs[0], anch + 0,  confW + 0,      boxW + 0L);
    decode_kernel<40, 40><<<4800,  256, 0, stream>>>(xs[1], anch + 6,  confW + 307200, boxW + 307200L * 4);
    decode_kernel<20, 20><<<1200,  256, 0, stream>>>(xs[2], anch + 12, confW + 384000, boxW + 384000L * 4);

    LvlParams P0{fs[0], 0L,      0L,      19200, 80, 80, 128};
    LvlParams P1{fs[1], 307200L, 51200L,  4800,  40, 40, 256};
    LvlParams P2{fs[2], 384000L, 153600L, 1200,  20, 20, 512};

    select_nms_gather_kernel<<<48, 256, 0, stream>>>(confW, boxW, (float*)d_out, P0, P1, P2);
}

// Round 4
// 89.605 us; speedup vs baseline: 4.9564x; 1.2847x over previous
//
#include <hip/hip_runtime.h>
#include <math.h>
#include <float.h>

#define MAX_DET 25
#define IOU_THRES 0.7f
#define MAX_WH 7680.0f
#define TOPK 256
#define MCAP 512

__device__ __forceinline__ float sigm(float v) {
#pragma clang fp contract(off)
    return 1.0f / (1.0f + expf(-v));
}

// ---------------- Decode: 16 lanes per candidate ----------------
template<int NY, int NX>
__global__ __launch_bounds__(256) void decode_kernel(
    const float* __restrict__ x, const float* __restrict__ anch,
    float* __restrict__ confW, float* __restrict__ boxW)
{
#pragma clang fp contract(off)
    constexpr int HW = NY * NX;
    constexpr int NPC = 3 * HW;
    constexpr int N = 16 * NPC;
    int t = blockIdx.x * 256 + threadIdx.x;
    int g = t >> 4;
    if (g >= N) return;
    int l16 = t & 15;
    const float* row = x + (long)g * 85;

    float bv = -FLT_MAX; int bc = 0;
#pragma unroll
    for (int j = 0; j < 5; ++j) {
        float v = row[5 + l16 + 16 * j];
        if (v > bv) { bv = v; bc = l16 + 16 * j; }
    }
#pragma unroll
    for (int off = 8; off; off >>= 1) {
        float ov = __shfl_xor(bv, off);
        int   oc = __shfl_xor(bc, off);
        if (ov > bv || (ov == bv && oc < bc)) { bv = ov; bc = oc; }
    }
    if (l16 != 0) return;

    float v0 = row[0], v1 = row[1], v2 = row[2], v3 = row[3], v4 = row[4];
    int i   = g % NPC;
    int a   = i / HW;
    int rem = i - a * HW;
    int gy  = rem / NX;
    int gx  = rem - gy * NX;

    float conf = sigm(bv) * sigm(v4);
    float cx = sigm(v0) * 2.0f + ((float)gx - 0.5f);
    float cy = sigm(v1) * 2.0f + ((float)gy - 0.5f);
    float tw = sigm(v2) * 2.0f, th = sigm(v3) * 2.0f;
    float w = (tw * tw) * anch[a * 2 + 0];
    float h = (th * th) * anch[a * 2 + 1];
    float x1 = cx - w / 2.0f, y1 = cy - h / 2.0f;
    float x2 = cx + w / 2.0f, y2 = cy + h / 2.0f;
    float offc = (float)bc * MAX_WH;

    confW[g] = conf;
    float4 bb = make_float4(x1 + offc, y1 + offc, x2 + offc, y2 + offc);
    *reinterpret_cast<float4*>(boxW + (long)g * 4) = bb;
}

// ---------------- Fused per-group: radix-select + sort + NMS ----------------
struct LvlParams {
    const float* feat;
    long candOff;
    long outOff;
    int npc, ny, nx, C;
};

template<int NPC>
__device__ __forceinline__ void run_group(
    const float* __restrict__ gconf, const float* __restrict__ boxW, long base4,
    unsigned long long* sk, unsigned* hist, float (*sbox)[4], float (*selBox)[4],
    int* selIdx, int* selValid, unsigned* wtot /*4*/, unsigned* misc /*4*/,
    int grp, int2* __restrict__ sel)
{
#pragma clang fp contract(off)
    constexpr int NR = (NPC + 255) / 256;
    const int tid = threadIdx.x;
    const int lane = tid & 63;
    const int wid = tid >> 6;

    // load this group's conf bits into registers (coalesced stripes)
    unsigned ub[NR];
#pragma unroll
    for (int j = 0; j < NR; ++j) {
        int idx = tid + j * 256;
        ub[j] = ((NPC % 256 == 0) || idx < NPC) ? __float_as_uint(gconf[idx]) : 0u;
    }
    if (tid < MAX_DET) selValid[tid] = 0;
    if (tid == 0) misc[0] = 0;
    for (int i = tid; i < MCAP; i += 256) sk[i] = 0ULL;

    // ---- exact top-TOPK threshold via 2-pass radix histogram ----
    unsigned B = 0, B2 = 0, K2 = 0;
    for (int pass = 0; pass < 2; ++pass) {
        for (int i = tid; i < 2048; i += 256) hist[i] = 0;
        __syncthreads();
#pragma unroll
        for (int j = 0; j < NR; ++j) {
            int idx = tid + j * 256;
            if ((NPC % 256 == 0) || idx < NPC) {
                unsigned bits = ub[j];
                if (pass == 0) atomicAdd(&hist[bits >> 19], 1u);
                else if ((bits >> 19) == B) atomicAdd(&hist[(bits >> 8) & 2047u], 1u);
            }
        }
        __syncthreads();
        unsigned part = 0;
        int hb = tid * 8;
#pragma unroll
        for (int i = 0; i < 8; ++i) part += hist[hb + i];
        // inclusive suffix within wave
        unsigned s = part;
#pragma unroll
        for (int d = 1; d < 64; d <<= 1) {
            unsigned v = __shfl_down(s, d);
            if (lane < 64 - d) s += v;
        }
        if (lane == 0) wtot[wid] = s;
        __syncthreads();
        unsigned S = s;
        for (int w = wid + 1; w < 4; ++w) S += wtot[w];
        unsigned Ktgt = (pass == 0) ? TOPK : K2;
        if (S >= Ktgt && S - part < Ktgt) {     // unique crossing thread
            unsigned acc = S - part;
            for (int i = 7; i >= 0; --i) {
                unsigned h = hist[hb + i];
                acc += h;
                if (acc >= Ktgt) { misc[2] = (unsigned)(hb + i); misc[3] = acc - h; break; }
            }
        }
        __syncthreads();
        if (pass == 0) { B = misc[2]; K2 = Ktgt - misc[3]; }
        else           { B2 = misc[2]; }
        __syncthreads();
    }
    unsigned T = (B << 19) | (B2 << 8);

    // ---- collect {bits >= T} into LDS key list ----
#pragma unroll
    for (int j = 0; j < NR; ++j) {
        int idx = tid + j * 256;
        bool in = ((NPC % 256 == 0) || idx < NPC) && (ub[j] >= T);
        if (in) {
            unsigned pos = atomicAdd(&misc[0], 1u);
            if (pos < MCAP)
                sk[pos] = ((unsigned long long)ub[j] << 32) | (unsigned)(~idx);
        }
    }
    __syncthreads();
    unsigned cn = misc[0];
    int n = (cn < (unsigned)MCAP) ? (int)cn : MCAP;

    // ---- bitonic sort descending (unique keys -> deterministic order) ----
    for (int ksz = 2; ksz <= MCAP; ksz <<= 1) {
        for (int j = ksz >> 1; j > 0; j >>= 1) {
            for (int i = tid; i < MCAP; i += 256) {
                int ixj = i ^ j;
                if (ixj > i) {
                    unsigned long long a = sk[i], bb = sk[ixj];
                    bool desc = ((i & ksz) == 0);
                    if (desc ? (a < bb) : (a > bb)) { sk[i] = bb; sk[ixj] = a; }
                }
            }
            __syncthreads();
        }
    }

    // ---- prefetch top-256 boxes to LDS ----
    if (tid < n) {
        int idx = (int)(~(unsigned)sk[tid]);
        const float4 bb4 = *reinterpret_cast<const float4*>(boxW + base4 + (long)idx * 4);
        sbox[tid][0] = bb4.x; sbox[tid][1] = bb4.y; sbox[tid][2] = bb4.z; sbox[tid][3] = bb4.w;
    }
    __syncthreads();

    // ---- serial greedy NMS on wave 0 ----
    if (tid < 64) {
        int k = 0;
        for (int t = 0; t < n && k < MAX_DET; ++t) {
            float cx1, cy1, cx2, cy2;
            if (t < 256) {
                cx1 = sbox[t][0]; cy1 = sbox[t][1]; cx2 = sbox[t][2]; cy2 = sbox[t][3];
            } else {
                int idx = (int)(~(unsigned)sk[t]);
                const float* bp = boxW + base4 + (long)idx * 4;
                cx1 = bp[0]; cy1 = bp[1]; cx2 = bp[2]; cy2 = bp[3];
            }
            bool rej = false;
            if (tid < k) {
                float sx1 = selBox[tid][0], sy1 = selBox[tid][1];
                float sx2 = selBox[tid][2], sy2 = selBox[tid][3];
                float ltx = fmaxf(sx1, cx1), lty = fmaxf(sy1, cy1);
                float rbx = fminf(sx2, cx2), rby = fminf(sy2, cy2);
                float ww = fmaxf(rbx - ltx, 0.0f), hh = fmaxf(rby - lty, 0.0f);
                float inter = ww * hh;
                float area1 = (sx2 - sx1) * (sy2 - sy1);
                float area2 = (cx2 - cx1) * (cy2 - cy1);
                float iou = inter / (area1 + area2 - inter);
                rej = iou > IOU_THRES;
            }
            rej = __any(rej);
            if (!rej) {
                if (tid == 0) {
                    selIdx[k] = (int)(~(unsigned)sk[t]);
                    selValid[k] = 1;
                    selBox[k][0] = cx1; selBox[k][1] = cy1;
                    selBox[k][2] = cx2; selBox[k][3] = cy2;
                }
                k++;
            }
        }
    }
    __syncthreads();

    // ---- write selection records for the gather kernel ----
    if (tid < MAX_DET)
        sel[grp * MAX_DET + tid] = make_int2(selIdx[tid], selValid[tid]);
}

__global__ __launch_bounds__(256) void select_nms_kernel(
    const float* __restrict__ confW, const float* __restrict__ boxW,
    int2* __restrict__ sel, LvlParams p0, LvlParams p1, LvlParams p2)
{
    __shared__ unsigned long long sk[MCAP];
    __shared__ unsigned hist[2048];
    __shared__ float sbox[256][4];
    __shared__ float selBox[MAX_DET][4];
    __shared__ int   selIdx[MAX_DET];
    __shared__ int   selValid[MAX_DET];
    __shared__ unsigned wtot[4];
    __shared__ unsigned misc[4];

    int grp = blockIdx.x;
    int lvl = grp >> 4, b = grp & 15;
    if (lvl == 0) {
        long base = p0.candOff + (long)b * p0.npc;
        run_group<19200>(confW + base, boxW, base * 4, sk, hist, sbox, selBox, selIdx, selValid, wtot, misc, grp, sel);
    } else if (lvl == 1) {
        long base = p1.candOff + (long)b * p1.npc;
        run_group<4800>(confW + base, boxW, base * 4, sk, hist, sbox, selBox, selIdx, selValid, wtot, misc, grp, sel);
    } else {
        long base = p2.candOff + (long)b * p2.npc;
        run_group<1200>(confW + base, boxW, base * 4, sk, hist, sbox, selBox, selIdx, selValid, wtot, misc, grp, sel);
    }
}

// ---------------- Gather: one block per output slot (48*25 = 1200 blocks) ----------------
__global__ __launch_bounds__(256) void gather_kernel(
    const int2* __restrict__ sel, float* __restrict__ out,
    LvlParams p0, LvlParams p1, LvlParams p2)
{
    int bid = blockIdx.x;
    int grp = bid / MAX_DET, k = bid - grp * MAX_DET;
    int lvl = grp >> 4, b = grp & 15;
    LvlParams p = (lvl == 0) ? p0 : ((lvl == 1) ? p1 : p2);
    int2 sv = sel[bid];
    long obase = p.outOff + ((long)b * MAX_DET + k) * p.C;
    const int hw = p.ny * p.nx;
    if (sv.y) {
        int rem = sv.x % hw;
        int gy = rem / p.nx, gx = rem - gy * p.nx;
        const float* f = p.feat + (long)b * p.C * hw + (long)gy * p.nx + gx;
        for (int c = threadIdx.x; c < p.C; c += 256)
            out[obase + c] = f[(long)c * hw];
    } else {
        for (int c = threadIdx.x; c < p.C; c += 256)
            out[obase + c] = 0.0f;
    }
}

extern "C" void kernel_launch(void* const* d_in, const int* in_sizes, int n_in,
                              void* d_out, int out_size, void* d_ws, size_t ws_size,
                              hipStream_t stream)
{
    const float* xs[3] = {nullptr, nullptr, nullptr};
    const float* fs[3] = {nullptr, nullptr, nullptr};
    const float* anch  = nullptr;
    for (int i = 0; i < n_in; ++i) {
        const float* p = (const float*)d_in[i];
        switch (in_sizes[i]) {
            case 26112000: xs[0] = p; break;
            case 6528000:  xs[1] = p; break;
            case 1632000:  xs[2] = p; break;
            case 13107200: fs[0] = p; break;
            case 6553600:  fs[1] = p; break;
            case 3276800:  fs[2] = p; break;
            case 18:       anch  = p; break;
        }
    }

    char* wsb = (char*)d_ws;
    float* confW = (float*)wsb;                  // 403200 f32
    float* boxW  = (float*)(wsb + 1612800L);     // 403200 f32x4
    int2*  sel   = (int2*)(wsb + 8064000L);      // 48*25 int2

    decode_kernel<80, 80><<<19200, 256, 0, stream>>>(xs[0], anch + 0,  confW + 0,      boxW + 0L);
    decode_kernel<40, 40><<<4800,  256, 0, stream>>>(xs[1], anch + 6,  confW + 307200, boxW + 307200L * 4);
    decode_kernel<20, 20><<<1200,  256, 0, stream>>>(xs[2], anch + 12, confW + 384000, boxW + 384000L * 4);

    LvlParams P0{fs[0], 0L,      0L,      19200, 80, 80, 128};
    LvlParams P1{fs[1], 307200L, 51200L,  4800,  40, 40, 256};
    LvlParams P2{fs[2], 384000L, 153600L, 1200,  20, 20, 512};

    select_nms_kernel<<<48, 256, 0, stream>>>(confW, boxW, sel, P0, P1, P2);
    gather_kernel<<<48 * MAX_DET, 256, 0, stream>>>(sel, (float*)d_out, P0, P1, P2);
}

// Round 5
// 73.708 us; speedup vs baseline: 6.0253x; 1.2157x over previous
//
#include <hip/hip_runtime.h>
#include <math.h>
#include <float.h>

#define MAX_DET 25
#define IOU_THRES 0.7f
#define MAX_WH 7680.0f
#define TOPK 256
#define MCAP 512

__device__ __forceinline__ float sigm(float v) {
#pragma clang fp contract(off)
    return 1.0f / (1.0f + expf(-v));
}

// ---------------- Decode: 16 lanes per candidate, all 3 levels in one launch ----------------
template<int NY, int NX>
__device__ __forceinline__ void decode_body(
    int bid, const float* __restrict__ x, const float* __restrict__ anch,
    float* __restrict__ confW, float* __restrict__ boxW)
{
#pragma clang fp contract(off)
    constexpr int HW = NY * NX;
    constexpr int NPC = 3 * HW;
    constexpr int N = 16 * NPC;
    int t = bid * 256 + threadIdx.x;
    int g = t >> 4;
    if (g >= N) return;
    int l16 = t & 15;
    const float* row = x + (long)g * 85;

    float bv = -FLT_MAX; int bc = 0;
#pragma unroll
    for (int j = 0; j < 5; ++j) {
        float v = row[5 + l16 + 16 * j];
        if (v > bv) { bv = v; bc = l16 + 16 * j; }
    }
#pragma unroll
    for (int off = 8; off; off >>= 1) {
        float ov = __shfl_xor(bv, off);
        int   oc = __shfl_xor(bc, off);
        if (ov > bv || (ov == bv && oc < bc)) { bv = ov; bc = oc; }
    }
    if (l16 != 0) return;

    float v0 = row[0], v1 = row[1], v2 = row[2], v3 = row[3], v4 = row[4];
    int i   = g % NPC;
    int a   = i / HW;
    int rem = i - a * HW;
    int gy  = rem / NX;
    int gx  = rem - gy * NX;

    float conf = sigm(bv) * sigm(v4);
    float cx = sigm(v0) * 2.0f + ((float)gx - 0.5f);
    float cy = sigm(v1) * 2.0f + ((float)gy - 0.5f);
    float tw = sigm(v2) * 2.0f, th = sigm(v3) * 2.0f;
    float w = (tw * tw) * anch[a * 2 + 0];
    float h = (th * th) * anch[a * 2 + 1];
    float x1 = cx - w / 2.0f, y1 = cy - h / 2.0f;
    float x2 = cx + w / 2.0f, y2 = cy + h / 2.0f;
    float offc = (float)bc * MAX_WH;

    confW[g] = conf;
    float4 bb = make_float4(x1 + offc, y1 + offc, x2 + offc, y2 + offc);
    *reinterpret_cast<float4*>(boxW + (long)g * 4) = bb;
}

__global__ __launch_bounds__(256) void decode_all_kernel(
    const float* __restrict__ x0, const float* __restrict__ x1, const float* __restrict__ x2,
    const float* __restrict__ anch, float* __restrict__ confW, float* __restrict__ boxW)
{
    int bid = blockIdx.x;
    if (bid < 19200)       decode_body<80, 80>(bid,          x0, anch + 0,  confW,          boxW);
    else if (bid < 24000)  decode_body<40, 40>(bid - 19200,  x1, anch + 6,  confW + 307200, boxW + 307200L * 4);
    else                   decode_body<20, 20>(bid - 24000,  x2, anch + 12, confW + 384000, boxW + 384000L * 4);
}

// ---------------- Fused per-group: radix-select + sort + NMS (conf in LDS) ----------------
struct LvlParams {
    const float* feat;
    long candOff;
    long outOff;
    int npc, ny, nx, C;
};

template<int NPC>
__device__ __forceinline__ void run_group(
    const float* __restrict__ gconf, const float* __restrict__ boxW, long base4,
    float* sconf, unsigned long long* sk, unsigned* hist, float (*sbox)[4],
    float (*selBox)[4], int* selIdx, int* selValid, unsigned* wtot /*16*/,
    unsigned* misc /*4*/, int grp, int2* __restrict__ sel)
{
#pragma clang fp contract(off)
    const int tid = threadIdx.x;
    const int lane = tid & 63;
    const int wid = tid >> 6;

    // stage conf in LDS (coalesced; no register spill)
    for (int i = tid; i < NPC; i += 1024) sconf[i] = gconf[i];
    if (tid < MAX_DET) selValid[tid] = 0;
    if (tid == 0) misc[0] = 0;
    for (int i = tid; i < MCAP; i += 1024) sk[i] = 0ULL;

    // ---- exact top-TOPK threshold via 2-pass radix histogram ----
    unsigned B = 0, B2 = 0, K2 = 0;
    for (int pass = 0; pass < 2; ++pass) {
        for (int i = tid; i < 2048; i += 1024) hist[i] = 0;
        __syncthreads();
        for (int i = tid; i < NPC; i += 1024) {
            unsigned bits = __float_as_uint(sconf[i]);
            if (pass == 0) atomicAdd(&hist[bits >> 19], 1u);
            else if ((bits >> 19) == B) atomicAdd(&hist[(bits >> 8) & 2047u], 1u);
        }
        __syncthreads();
        // suffix count from the top: thread tid owns bins {2tid, 2tid+1}
        unsigned part = hist[tid * 2] + hist[tid * 2 + 1];
        unsigned s = part;
#pragma unroll
        for (int d = 1; d < 64; d <<= 1) {
            unsigned v = __shfl_down(s, d);
            if (lane < 64 - d) s += v;
        }
        if (lane == 0) wtot[wid] = s;
        __syncthreads();
        unsigned S = s;
        for (int w = wid + 1; w < 16; ++w) S += wtot[w];
        unsigned Ktgt = (pass == 0) ? TOPK : K2;
        if (S >= Ktgt && S - part < Ktgt) {     // unique crossing thread
            unsigned acc = S - part;
            for (int i = 1; i >= 0; --i) {
                unsigned h = hist[tid * 2 + i];
                acc += h;
                if (acc >= Ktgt) { misc[2] = (unsigned)(tid * 2 + i); misc[3] = acc - h; break; }
            }
        }
        __syncthreads();
        if (pass == 0) { B = misc[2]; K2 = Ktgt - misc[3]; }
        else           { B2 = misc[2]; }
        __syncthreads();
    }
    unsigned T = (B << 19) | (B2 << 8);

    // ---- collect {bits >= T} into LDS key list ----
    for (int i = tid; i < NPC; i += 1024) {
        unsigned bits = __float_as_uint(sconf[i]);
        if (bits >= T) {
            unsigned pos = atomicAdd(&misc[0], 1u);
            if (pos < MCAP)
                sk[pos] = ((unsigned long long)bits << 32) | (unsigned)(~i);
        }
    }
    __syncthreads();
    unsigned cn = misc[0];
    int n = (cn < (unsigned)MCAP) ? (int)cn : MCAP;

    // ---- bitonic sort descending (unique keys -> deterministic order) ----
    for (int ksz = 2; ksz <= MCAP; ksz <<= 1) {
        for (int j = ksz >> 1; j > 0; j >>= 1) {
            for (int i = tid; i < MCAP; i += 1024) {
                int ixj = i ^ j;
                if (ixj > i) {
                    unsigned long long a = sk[i], bb = sk[ixj];
                    bool desc = ((i & ksz) == 0);
                    if (desc ? (a < bb) : (a > bb)) { sk[i] = bb; sk[ixj] = a; }
                }
            }
            __syncthreads();
        }
    }

    // ---- prefetch top-256 boxes to LDS ----
    if (tid < 256 && tid < n) {
        int idx = (int)(~(unsigned)sk[tid]);
        const float4 bb4 = *reinterpret_cast<const float4*>(boxW + base4 + (long)idx * 4);
        sbox[tid][0] = bb4.x; sbox[tid][1] = bb4.y; sbox[tid][2] = bb4.z; sbox[tid][3] = bb4.w;
    }
    __syncthreads();

    // ---- serial greedy NMS on wave 0 ----
    if (tid < 64) {
        int k = 0;
        for (int t = 0; t < n && k < MAX_DET; ++t) {
            float cx1, cy1, cx2, cy2;
            if (t < 256) {
                cx1 = sbox[t][0]; cy1 = sbox[t][1]; cx2 = sbox[t][2]; cy2 = sbox[t][3];
            } else {
                int idx = (int)(~(unsigned)sk[t]);
                const float* bp = boxW + base4 + (long)idx * 4;
                cx1 = bp[0]; cy1 = bp[1]; cx2 = bp[2]; cy2 = bp[3];
            }
            bool rej = false;
            if (tid < k) {
                float sx1 = selBox[tid][0], sy1 = selBox[tid][1];
                float sx2 = selBox[tid][2], sy2 = selBox[tid][3];
                float ltx = fmaxf(sx1, cx1), lty = fmaxf(sy1, cy1);
                float rbx = fminf(sx2, cx2), rby = fminf(sy2, cy2);
                float ww = fmaxf(rbx - ltx, 0.0f), hh = fmaxf(rby - lty, 0.0f);
                float inter = ww * hh;
                float area1 = (sx2 - sx1) * (sy2 - sy1);
                float area2 = (cx2 - cx1) * (cy2 - cy1);
                float iou = inter / (area1 + area2 - inter);
                rej = iou > IOU_THRES;
            }
            rej = __any(rej);
            if (!rej) {
                if (tid == 0) {
                    selIdx[k] = (int)(~(unsigned)sk[t]);
                    selValid[k] = 1;
                    selBox[k][0] = cx1; selBox[k][1] = cy1;
                    selBox[k][2] = cx2; selBox[k][3] = cy2;
                }
                k++;
            }
        }
    }
    __syncthreads();

    // ---- write selection records for the gather kernel ----
    if (tid < MAX_DET)
        sel[grp * MAX_DET + tid] = make_int2(selIdx[tid], selValid[tid]);
}

__global__ __launch_bounds__(1024) void select_nms_kernel(
    const float* __restrict__ confW, const float* __restrict__ boxW,
    int2* __restrict__ sel, LvlParams p0, LvlParams p1, LvlParams p2)
{
    __shared__ float sconf[19200];
    __shared__ unsigned long long sk[MCAP];
    __shared__ unsigned hist[2048];
    __shared__ float sbox[256][4];
    __shared__ float selBox[MAX_DET][4];
    __shared__ int   selIdx[MAX_DET];
    __shared__ int   selValid[MAX_DET];
    __shared__ unsigned wtot[16];
    __shared__ unsigned misc[4];

    int grp = blockIdx.x;
    int lvl = grp >> 4, b = grp & 15;
    if (lvl == 0) {
        long base = p0.candOff + (long)b * p0.npc;
        run_group<19200>(confW + base, boxW, base * 4, sconf, sk, hist, sbox, selBox, selIdx, selValid, wtot, misc, grp, sel);
    } else if (lvl == 1) {
        long base = p1.candOff + (long)b * p1.npc;
        run_group<4800>(confW + base, boxW, base * 4, sconf, sk, hist, sbox, selBox, selIdx, selValid, wtot, misc, grp, sel);
    } else {
        long base = p2.candOff + (long)b * p2.npc;
        run_group<1200>(confW + base, boxW, base * 4, sconf, sk, hist, sbox, selBox, selIdx, selValid, wtot, misc, grp, sel);
    }
}

// ---------------- Gather: one block per output slot (48*25 = 1200 blocks) ----------------
__global__ __launch_bounds__(256) void gather_kernel(
    const int2* __restrict__ sel, float* __restrict__ out,
    LvlParams p0, LvlParams p1, LvlParams p2)
{
    int bid = blockIdx.x;
    int grp = bid / MAX_DET, k = bid - grp * MAX_DET;
    int lvl = grp >> 4, b = grp & 15;
    LvlParams p = (lvl == 0) ? p0 : ((lvl == 1) ? p1 : p2);
    int2 sv = sel[bid];
    long obase = p.outOff + ((long)b * MAX_DET + k) * p.C;
    const int hw = p.ny * p.nx;
    if (sv.y) {
        int rem = sv.x % hw;
        int gy = rem / p.nx, gx = rem - gy * p.nx;
        const float* f = p.feat + (long)b * p.C * hw + (long)gy * p.nx + gx;
        for (int c = threadIdx.x; c < p.C; c += 256)
            out[obase + c] = f[(long)c * hw];
    } else {
        for (int c = threadIdx.x; c < p.C; c += 256)
            out[obase + c] = 0.0f;
    }
}

extern "C" void kernel_launch(void* const* d_in, const int* in_sizes, int n_in,
                              void* d_out, int out_size, void* d_ws, size_t ws_size,
                              hipStream_t stream)
{
    const float* xs[3] = {nullptr, nullptr, nullptr};
    const float* fs[3] = {nullptr, nullptr, nullptr};
    const float* anch  = nullptr;
    for (int i = 0; i < n_in; ++i) {
        const float* p = (const float*)d_in[i];
        switch (in_sizes[i]) {
            case 26112000: xs[0] = p; break;
            case 6528000:  xs[1] = p; break;
            case 1632000:  xs[2] = p; break;
            case 13107200: fs[0] = p; break;
            case 6553600:  fs[1] = p; break;
            case 3276800:  fs[2] = p; break;
            case 18:       anch  = p; break;
        }
    }

    char* wsb = (char*)d_ws;
    float* confW = (float*)wsb;                  // 403200 f32
    float* boxW  = (float*)(wsb + 1612800L);     // 403200 f32x4
    int2*  sel   = (int2*)(wsb + 8064000L);      // 48*25 int2

    decode_all_kernel<<<25200, 256, 0, stream>>>(xs[0], xs[1], xs[2], anch, confW, boxW);

    LvlParams P0{fs[0], 0L,      0L,      19200, 80, 80, 128};
    LvlParams P1{fs[1], 307200L, 51200L,  4800,  40, 40, 256};
    LvlParams P2{fs[2], 384000L, 153600L, 1200,  20, 20, 512};

    select_nms_kernel<<<48, 1024, 0, stream>>>(confW, boxW, sel, P0, P1, P2);
    gather_kernel<<<48 * MAX_DET, 256, 0, stream>>>(sel, (float*)d_out, P0, P1, P2);
}